// Round 8
// baseline (339.015 us; speedup 1.0000x reference)
//
#include <hip/hip_runtime.h>

#define NB 8192
#define NT 50

typedef short short8 __attribute__((ext_vector_type(8)));
typedef float f32x4 __attribute__((ext_vector_type(4)));

__device__ __forceinline__ float leaky(float x) { return x > 0.0f ? x : 0.3f * x; }

__device__ __forceinline__ unsigned short bf16rn(float v) {
    unsigned int u = __float_as_uint(v);
    unsigned int r = u + 0x7FFFu + ((u >> 16) & 1u);
    return (unsigned short)(r >> 16);
}
__device__ __forceinline__ float bf16tof(unsigned short h) {
    return __uint_as_float(((unsigned int)h) << 16);
}
__device__ __forceinline__ unsigned int pk2(unsigned short a, unsigned short b) {
    return (unsigned int)a | ((unsigned int)b << 16);
}

__device__ __forceinline__ float idm_act_f(float v, float dv, float dx,
                                           float inv_v0, float tg, float jam,
                                           float amax, float inv_gd) {
    dx = fminf(fmaxf(dx, 0.1f), 500.0f);
    float gap = tg * v + v * dv * inv_gd;
    float dg = jam + fmaxf(gap, 0.0f);
    float r = v * inv_v0;
    float r2 = r * r;
    float r4 = r2 * r2;
    float q = dg / dx;
    float act = amax * (1.0f - r4 - q * q);
    return fminf(fmaxf(act, -6.0f), 6.0f);
}

extern "C" __global__ __launch_bounds__(512, 4)
void idm_rollout_kernel(const float* __restrict__ idm_params,
                        const float* __restrict__ proj_latent,
                        const float* __restrict__ enc_h,
                        const float* __restrict__ idm_s,
                        const float* __restrict__ merger_cs,
                        const float* __restrict__ scaler_mean,
                        const float* __restrict__ scaler_var,
                        const float* __restrict__ W1,
                        const float* __restrict__ b1,
                        const float* __restrict__ W2,
                        const float* __restrict__ b2,
                        const float* __restrict__ Wf,
                        const float* __restrict__ bfp,
                        const float* __restrict__ Wm,
                        const float* __restrict__ bmp,
                        float* __restrict__ out)
{
    // h1 3-level fragments: [kchunk][lvl][slot-lane][e]
    __shared__ __align__(16) short s_a[4][3][64][8];       // 12 KB
    // W2^T level-2 fragments (per-thread private slice, LDS to save VGPR)
    __shared__ __align__(16) short s_w2l2[4][512][8];      // 32 KB
    // head partials: [elem][2*jtile + {f,m}], padded row stride 20
    __shared__ __align__(16) float s_part[16][20];         // 1.25 KB

    const int tid = threadIdx.x;       // 0..511
    const int w   = tid >> 6;          // wave = jtile (layer2) = ktile (layer1)
    const int l   = tid & 63;
    const int lm  = l & 15;            // this lane's batch element (within block)
    const int lq  = l >> 4;
    const int b0  = blockIdx.x * 16;
    const int bm  = b0 + lm;
    const int colbase = w * 16 + lq * 4;   // this lane's 4 output cols (D rows)

    // ---- W1dyn^T A-frags (3-level, static): A[lm][r=lq*8+e] = W1d[r][w*16+lm] ----
    short8 W1T0, W1T1, W1T2;
    #pragma unroll
    for (int e = 0; e < 8; ++e) {
        const int r = lq * 8 + e;
        float v = 0.0f;
        if (r < 11) {
            v = W1[(256 + r) * 128 + w * 16 + lm];
            if (r < 8) v *= 1.0f / sqrtf(scaler_var[r]);
        }
        const unsigned short q0 = bf16rn(v);
        const float r1 = v - bf16tof(q0);
        const unsigned short q1 = bf16rn(r1);
        W1T0[e] = (short)q0; W1T1[e] = (short)q1;
        W1T2[e] = (short)bf16rn(r1 - bf16tof(q1));
    }

    // ---- W2^T A-frags: lvl0/1 in regs, lvl2 in LDS ----
    short8 W2T0[4], W2T1[4];
    #pragma unroll
    for (int kc = 0; kc < 4; ++kc) {
        short8 l2;
        #pragma unroll
        for (int e = 0; e < 8; ++e) {
            const int k = kc * 32 + lq * 8 + e;
            const float v = W2[k * 128 + w * 16 + lm];
            const unsigned short q0 = bf16rn(v);
            const float r1 = v - bf16tof(q0);
            const unsigned short q1 = bf16rn(r1);
            W2T0[kc][e] = (short)q0; W2T1[kc][e] = (short)q1;
            l2[e] = (short)bf16rn(r1 - bf16tof(q1));
        }
        *(short8*)&s_w2l2[kc][tid][0] = l2;
    }

    // ---- head constants for this lane's 4 cols ----
    const f32x4 b2r = *(const f32x4*)&b2[colbase];
    const f32x4 wfr = *(const f32x4*)&Wf[colbase];
    const f32x4 wmr = *(const f32x4*)&Wm[colbase];
    const float bfv = bfp[0];
    const float bmv = bmp[0];

    // ---- hpre for (elem lm, cols colbase..+3): exact coverage, no duplication ----
    f32x4 hp = *(const f32x4*)&b1[colbase];
    {
        const float* xl0 = proj_latent + (size_t)bm * 128;
        const float* xl1 = enc_h + (size_t)bm * 128;
        #pragma unroll 2
        for (int r0 = 0; r0 < 128; r0 += 4) {
            const f32x4 x = *(const f32x4*)&xl0[r0];
            #pragma unroll
            for (int j = 0; j < 4; ++j) {
                const f32x4 wq = *(const f32x4*)&W1[(r0 + j) * 128 + colbase];
                hp += x[j] * wq;
            }
        }
        #pragma unroll 2
        for (int r0 = 0; r0 < 128; r0 += 4) {
            const f32x4 x = *(const f32x4*)&xl1[r0];
            #pragma unroll
            for (int j = 0; j < 4; ++j) {
                const f32x4 wq = *(const f32x4*)&W1[(128 + r0 + j) * 128 + colbase];
                hp += x[j] * wq;
            }
        }
        #pragma unroll
        for (int rr = 0; rr < 8; ++rr) {   // fold -(mean*inv_std)@W1env
            const float c = scaler_mean[rr] * (1.0f / sqrtf(scaler_var[rr]));
            const f32x4 wq = *(const f32x4*)&W1[(256 + rr) * 128 + colbase];
            hp -= c * wq;
        }
    }

    // ---- per-lane dynamics state for elem bm (redundant across lq and waves) ----
    float ego_v_r, ego_a_r, ego_x_r, disp_r;
    float ef_dv_r, ef_dx_r, em_dv_r, em_dx_r;
    float c_fa, c_fv, c_m0, c_m1, c_m2;
    {
        const float* sr = idm_s + (size_t)bm * 714;     // 51*14
        const float* mr = merger_cs + (size_t)bm * 150;
        ego_v_r = sr[0]; ego_a_r = sr[11]; ego_x_r = sr[3]; disp_r = 0.0f;
        const float fv0 = sr[1], mv0 = sr[2], fx0 = sr[4], mx0 = sr[5];
        c_fa = sr[12];
        const float me0 = sr[13];
        c_fv = fv0;
        ef_dx_r = fx0 - ego_x_r;
        em_dx_r = (mx0 - ego_x_r) * me0 + (1.0f - me0) * 100.0f;
        ef_dv_r = ego_v_r - fv0;
        em_dv_r = (ego_v_r - mv0) * me0;
        c_m0 = mr[0]; c_m1 = mr[1]; c_m2 = mr[2];
    }
    const float ptg    = idm_params[bm * 5 + 1];
    const float pjam   = idm_params[bm * 5 + 2];
    const float pamax  = idm_params[bm * 5 + 3];
    const float pinv_v0 = 1.0f / idm_params[bm * 5 + 0];
    const float pinv_gd = 1.0f / (2.0f * sqrtf(pamax * idm_params[bm * 5 + 4]));

    float* out_disp = out;
    float* out_act  = out + NB * 51;
    float* out_fat  = out + NB * (51 + 50);
    float* out_mat  = out + NB * (51 + 100);
    if (tid < 16) out_disp[bm * 51] = 0.0f;

    // producer slot for s_a writes
    const int kcw = w >> 1;
    const int Lw  = lm + 16 * ((w & 1) * 2 + (lq >> 1));
    const int e0w = (lq & 1) * 4;

    for (int t = 0; t < NT; ++t) {
        // ---- prefetch next-step exogenous scalars (own elem) ----
        float nf_fv = 0, nf_mv = 0, nf_fx = 0, nf_mx = 0, nf_fa = 0, nf_me = 0;
        float nf_m0 = 0, nf_m1 = 0, nf_m2 = 0;
        if (t + 1 < NT) {
            const float* sp = idm_s + (size_t)bm * 714 + (t + 1) * 14;
            nf_fv = sp[1]; nf_mv = sp[2]; nf_fx = sp[4]; nf_mx = sp[5];
            nf_fa = sp[12]; nf_me = sp[13];
            const float* mp = merger_cs + (size_t)bm * 150 + (t + 1) * 3;
            nf_m0 = mp[0]; nf_m1 = mp[1]; nf_m2 = mp[2];
        }

        // ---- phase A: layer1 via swapped MFMA (A=W1dT static, B=env lane-local) ----
        float bv[8];
        #pragma unroll
        for (int e = 0; e < 8; ++e) bv[e] = 0.0f;
        if (lq == 0) {
            bv[0] = ego_a_r; bv[1] = c_fa;    bv[2] = ego_v_r; bv[3] = c_fv;
            bv[4] = ef_dv_r; bv[5] = ef_dx_r; bv[6] = em_dv_r; bv[7] = em_dx_r;
        } else if (lq == 1) {
            bv[0] = c_m0; bv[1] = c_m1; bv[2] = c_m2;
        }
        short8 E0, E1, E2;
        #pragma unroll
        for (int e = 0; e < 8; ++e) {
            const float v = bv[e];
            const unsigned short q0 = bf16rn(v);
            const float r1 = v - bf16tof(q0);
            const unsigned short q1 = bf16rn(r1);
            E0[e] = (short)q0; E1[e] = (short)q1;
            E2[e] = (short)bf16rn(r1 - bf16tof(q1));
        }
        f32x4 d1a = {0,0,0,0}, d1b = {0,0,0,0}, d1c = {0,0,0,0};
        d1a = __builtin_amdgcn_mfma_f32_16x16x32_bf16(W1T0, E0, d1a, 0, 0, 0);
        d1b = __builtin_amdgcn_mfma_f32_16x16x32_bf16(W1T0, E1, d1b, 0, 0, 0);
        d1b = __builtin_amdgcn_mfma_f32_16x16x32_bf16(W1T1, E0, d1b, 0, 0, 0);
        d1c = __builtin_amdgcn_mfma_f32_16x16x32_bf16(W1T1, E1, d1c, 0, 0, 0);
        d1c = __builtin_amdgcn_mfma_f32_16x16x32_bf16(W1T0, E2, d1c, 0, 0, 0);
        d1c = __builtin_amdgcn_mfma_f32_16x16x32_bf16(W1T2, E0, d1c, 0, 0, 0);

        // lane now holds h1[elem=lm][col = colbase + r]; split 3-level, share via s_a
        unsigned short a0[4], a1[4], a2[4];
        #pragma unroll
        for (int r = 0; r < 4; ++r) {
            const float hv = leaky(d1a[r] + d1b[r] + d1c[r] + hp[r]);
            const unsigned short q0 = bf16rn(hv);
            const float r1 = hv - bf16tof(q0);
            const unsigned short q1 = bf16rn(r1);
            a0[r] = q0; a1[r] = q1; a2[r] = bf16rn(r1 - bf16tof(q1));
        }
        *(uint2*)&s_a[kcw][0][Lw][e0w] = make_uint2(pk2(a0[0], a0[1]), pk2(a0[2], a0[3]));
        *(uint2*)&s_a[kcw][1][Lw][e0w] = make_uint2(pk2(a1[0], a1[1]), pk2(a1[2], a1[3]));
        *(uint2*)&s_a[kcw][2][Lw][e0w] = make_uint2(pk2(a2[0], a2[1]), pk2(a2[2], a2[3]));

        __syncthreads();   // B1: h1 fragments visible

        // ---- phase B: layer2 via swapped MFMA (A=W2T static, B=h1 frags) ----
        f32x4 aA = {0,0,0,0}, aB = {0,0,0,0}, aC = {0,0,0,0};
        #pragma unroll
        for (int kc = 0; kc < 4; ++kc) {
            const short8 x0 = *(const short8*)&s_a[kc][0][l][0];
            const short8 x1 = *(const short8*)&s_a[kc][1][l][0];
            const short8 x2 = *(const short8*)&s_a[kc][2][l][0];
            const short8 w2l2 = *(const short8*)&s_w2l2[kc][tid][0];
            aA = __builtin_amdgcn_mfma_f32_16x16x32_bf16(W2T0[kc], x0, aA, 0, 0, 0);
            aB = __builtin_amdgcn_mfma_f32_16x16x32_bf16(W2T0[kc], x1, aB, 0, 0, 0);
            aB = __builtin_amdgcn_mfma_f32_16x16x32_bf16(W2T1[kc], x0, aB, 0, 0, 0);
            aC = __builtin_amdgcn_mfma_f32_16x16x32_bf16(W2T1[kc], x1, aC, 0, 0, 0);
            aC = __builtin_amdgcn_mfma_f32_16x16x32_bf16(W2T0[kc], x2, aC, 0, 0, 0);
            aC = __builtin_amdgcn_mfma_f32_16x16x32_bf16(w2l2,    x0, aC, 0, 0, 0);
        }
        // lane holds h2[elem=lm][j = colbase + r] -> partial head scores
        float fsc = 0.0f, msc = 0.0f;
        #pragma unroll
        for (int r = 0; r < 4; ++r) {
            const float h2 = leaky(aA[r] + aB[r] + aC[r] + b2r[r]);
            fsc += h2 * wfr[r];
            msc += h2 * wmr[r];
        }
        // reduce over lq (lanes lm, lm+16, lm+32, lm+48): 2 swizzles per score
        fsc += __shfl_xor(fsc, 16); fsc += __shfl_xor(fsc, 32);
        msc += __shfl_xor(msc, 16); msc += __shfl_xor(msc, 32);
        if (l < 16) *(float2*)&s_part[lm][w * 2] = make_float2(fsc, msc);

        __syncthreads();   // B2: head partials visible

        // ---- phase C: dynamics, redundant on all lanes (own elem bm) ----
        {
            const f32x4 p0 = *(const f32x4*)&s_part[lm][0];
            const f32x4 p1 = *(const f32x4*)&s_part[lm][4];
            const f32x4 p2 = *(const f32x4*)&s_part[lm][8];
            const f32x4 p3 = *(const f32x4*)&s_part[lm][12];
            const float fsum = bfv + p0.x + p0.z + p1.x + p1.z + p2.x + p2.z + p3.x + p3.z;
            const float msum = bmv + p0.y + p0.w + p1.y + p1.w + p2.y + p2.w + p3.y + p3.w;

            const float f_sc = fminf(fmaxf(fsum, -20.0f), 20.0f);
            const float m_sc = fminf(fmaxf(msum, -20.0f), 20.0f);
            const float dsc = 5.0f * (f_sc - m_sc);
            float fatt;
            if (dsc >= 0.0f) { const float ex = __expf(-dsc); fatt = 1.0f / (1.0f + ex); }
            else             { const float ex = __expf(dsc);  fatt = ex / (1.0f + ex); }
            const float matt = 1.0f - fatt;

            const float efa = idm_act_f(ego_v_r, ef_dv_r, ef_dx_r,
                                        pinv_v0, ptg, pjam, pamax, pinv_gd);
            const float ema = idm_act_f(ego_v_r, em_dv_r, em_dx_r,
                                        pinv_v0, ptg, pjam, pamax, pinv_gd);
            const float a2n = fatt * efa + matt * ema;

            const float delta = ego_v_r * 0.1f + 0.005f * a2n;
            disp_r  += delta;
            ego_x_r += delta;
            ego_v_r += a2n * 0.1f;
            ego_a_r  = a2n;

            if (tid < 16) {
                out_disp[bm * 51 + t + 1] = disp_r;
                out_act [bm * 50 + t]     = a2n;
                out_fat [bm * 50 + t]     = fatt;
                out_mat [bm * 50 + t]     = matt;
            }

            if (t + 1 < NT) {
                ef_dx_r = nf_fx - ego_x_r;
                em_dx_r = (nf_mx - ego_x_r) * nf_me + (1.0f - nf_me) * 100.0f;
                ef_dv_r = ego_v_r - nf_fv;
                em_dv_r = (ego_v_r - nf_mv) * nf_me;
                c_fa = nf_fa; c_fv = nf_fv;
                c_m0 = nf_m0; c_m1 = nf_m1; c_m2 = nf_m2;
            }
        }
        // no 3rd barrier: s_a rewrite (t+1, after B2) is fenced by B2;
        // s_part rewrite (t+1, after B1(t+1)) is fenced by B1(t+1).
    }
}

extern "C" void kernel_launch(void* const* d_in, const int* in_sizes, int n_in,
                              void* d_out, int out_size, void* d_ws, size_t ws_size,
                              hipStream_t stream) {
    (void)in_sizes; (void)n_in; (void)d_ws; (void)ws_size; (void)out_size;
    const float* idm_params  = (const float*)d_in[0];
    const float* proj_latent = (const float*)d_in[1];
    const float* enc_h       = (const float*)d_in[2];
    const float* idm_s       = (const float*)d_in[3];
    const float* merger_cs   = (const float*)d_in[4];
    const float* scaler_mean = (const float*)d_in[5];
    const float* scaler_var  = (const float*)d_in[6];
    const float* W1          = (const float*)d_in[7];
    const float* b1          = (const float*)d_in[8];
    const float* W2          = (const float*)d_in[9];
    const float* b2          = (const float*)d_in[10];
    const float* Wf          = (const float*)d_in[11];
    const float* bfp         = (const float*)d_in[12];
    const float* Wm          = (const float*)d_in[13];
    const float* bmp         = (const float*)d_in[14];

    idm_rollout_kernel<<<dim3(NB / 16), dim3(512), 0, stream>>>(
        idm_params, proj_latent, enc_h, idm_s, merger_cs,
        scaler_mean, scaler_var, W1, b1, W2, b2, Wf, bfp, Wm, bmp,
        (float*)d_out);
}

// Round 9
// 285.789 us; speedup vs baseline: 1.1862x; 1.1862x over previous
//
#include <hip/hip_runtime.h>

#define NB 8192
#define NT 50

typedef short short8 __attribute__((ext_vector_type(8)));
typedef float f32x4 __attribute__((ext_vector_type(4)));

__device__ __forceinline__ float leaky(float x) { return x > 0.0f ? x : 0.3f * x; }

__device__ __forceinline__ unsigned short bf16rn(float v) {
    unsigned int u = __float_as_uint(v);
    unsigned int r = u + 0x7FFFu + ((u >> 16) & 1u);
    return (unsigned short)(r >> 16);
}
__device__ __forceinline__ float bf16tof(unsigned short h) {
    return __uint_as_float(((unsigned int)h) << 16);
}
__device__ __forceinline__ unsigned int pk2(unsigned short a, unsigned short b) {
    return (unsigned int)a | ((unsigned int)b << 16);
}

__device__ __forceinline__ float idm_act_f(float v, float dv, float dx,
                                           float inv_v0, float tg, float jam,
                                           float amax, float inv_gd) {
    dx = fminf(fmaxf(dx, 0.1f), 500.0f);
    float gap = tg * v + v * dv * inv_gd;
    float dg = jam + fmaxf(gap, 0.0f);
    float r = v * inv_v0;
    float r2 = r * r;
    float r4 = r2 * r2;
    float q = dg / dx;
    float act = amax * (1.0f - r4 - q * q);
    return fminf(fmaxf(act, -6.0f), 6.0f);
}

extern "C" __global__ __launch_bounds__(512, 2)
void idm_rollout_kernel(const float* __restrict__ idm_params,
                        const float* __restrict__ proj_latent,
                        const float* __restrict__ enc_h,
                        const float* __restrict__ idm_s,
                        const float* __restrict__ merger_cs,
                        const float* __restrict__ scaler_mean,
                        const float* __restrict__ scaler_var,
                        const float* __restrict__ W1,
                        const float* __restrict__ b1,
                        const float* __restrict__ W2,
                        const float* __restrict__ b2,
                        const float* __restrict__ Wf,
                        const float* __restrict__ bfp,
                        const float* __restrict__ Wm,
                        const float* __restrict__ bmp,
                        float* __restrict__ out)
{
    // h1 3-level fragments: [kchunk][lvl][slot-lane][e]
    __shared__ __align__(16) short s_a[4][3][64][8];       // 12 KB
    // W2^T level-2 fragments (per-thread private slice)
    __shared__ __align__(16) short s_w2l2[4][512][8];      // 32 KB
    // W1dyn^T level-1/2 fragments (per-thread private slice)
    __shared__ __align__(16) short s_w1t12[2][512][8];     // 16 KB
    // head partials: [elem][2*jtile + {f,m}], padded row stride 20
    __shared__ __align__(16) float s_part[16][20];         // 1.25 KB

    const int tid = threadIdx.x;       // 0..511
    const int w   = tid >> 6;          // wave = jtile (layer2) = ktile (layer1)
    const int l   = tid & 63;
    const int lm  = l & 15;            // this lane's batch element (within block)
    const int lq  = l >> 4;
    const int b0  = blockIdx.x * 16;
    const int bm  = b0 + lm;
    const int colbase = w * 16 + lq * 4;   // this lane's 4 output cols (D rows)

    // ---- W1dyn^T A-frags (3-level): lvl0 regs, lvl1/2 LDS ----
    short8 W1T0;
    {
        short8 t1, t2;
        #pragma unroll
        for (int e = 0; e < 8; ++e) {
            const int r = lq * 8 + e;
            float v = 0.0f;
            if (r < 11) {
                v = W1[(256 + r) * 128 + w * 16 + lm];
                if (r < 8) v *= 1.0f / sqrtf(scaler_var[r]);
            }
            const unsigned short q0 = bf16rn(v);
            const float r1 = v - bf16tof(q0);
            const unsigned short q1 = bf16rn(r1);
            W1T0[e] = (short)q0; t1[e] = (short)q1;
            t2[e] = (short)bf16rn(r1 - bf16tof(q1));
        }
        *(short8*)&s_w1t12[0][tid][0] = t1;
        *(short8*)&s_w1t12[1][tid][0] = t2;
    }

    // ---- W2^T A-frags: lvl0/1 in regs, lvl2 in LDS ----
    short8 W2T0[4], W2T1[4];
    #pragma unroll
    for (int kc = 0; kc < 4; ++kc) {
        short8 l2;
        #pragma unroll
        for (int e = 0; e < 8; ++e) {
            const int k = kc * 32 + lq * 8 + e;
            const float v = W2[k * 128 + w * 16 + lm];
            const unsigned short q0 = bf16rn(v);
            const float r1 = v - bf16tof(q0);
            const unsigned short q1 = bf16rn(r1);
            W2T0[kc][e] = (short)q0; W2T1[kc][e] = (short)q1;
            l2[e] = (short)bf16rn(r1 - bf16tof(q1));
        }
        *(short8*)&s_w2l2[kc][tid][0] = l2;
    }

    // ---- head constants for this lane's 4 cols ----
    const f32x4 b2r = *(const f32x4*)&b2[colbase];
    const f32x4 wfr = *(const f32x4*)&Wf[colbase];
    const f32x4 wmr = *(const f32x4*)&Wm[colbase];
    const float bfv = bfp[0];
    const float bmv = bmp[0];

    // ---- hpre for (elem lm, cols colbase..+3) ----
    f32x4 hp = *(const f32x4*)&b1[colbase];
    {
        const float* xl0 = proj_latent + (size_t)bm * 128;
        const float* xl1 = enc_h + (size_t)bm * 128;
        #pragma unroll 2
        for (int r0 = 0; r0 < 128; r0 += 4) {
            const f32x4 x = *(const f32x4*)&xl0[r0];
            #pragma unroll
            for (int j = 0; j < 4; ++j) {
                const f32x4 wq = *(const f32x4*)&W1[(r0 + j) * 128 + colbase];
                hp += x[j] * wq;
            }
        }
        #pragma unroll 2
        for (int r0 = 0; r0 < 128; r0 += 4) {
            const f32x4 x = *(const f32x4*)&xl1[r0];
            #pragma unroll
            for (int j = 0; j < 4; ++j) {
                const f32x4 wq = *(const f32x4*)&W1[(128 + r0 + j) * 128 + colbase];
                hp += x[j] * wq;
            }
        }
        #pragma unroll
        for (int rr = 0; rr < 8; ++rr) {   // fold -(mean*inv_std)@W1env
            const float c = scaler_mean[rr] * (1.0f / sqrtf(scaler_var[rr]));
            const f32x4 wq = *(const f32x4*)&W1[(256 + rr) * 128 + colbase];
            hp -= c * wq;
        }
    }

    // ---- per-lane dynamics state for elem bm (redundant across lanes) ----
    float ego_v_r, ego_a_r, ego_x_r, disp_r;
    float ef_dv_r, ef_dx_r, em_dv_r, em_dx_r;
    float c_fa, c_fv, c_m0, c_m1, c_m2;
    {
        const float* sr = idm_s + (size_t)bm * 714;     // 51*14
        const float* mr = merger_cs + (size_t)bm * 150;
        ego_v_r = sr[0]; ego_a_r = sr[11]; ego_x_r = sr[3]; disp_r = 0.0f;
        const float fv0 = sr[1], mv0 = sr[2], fx0 = sr[4], mx0 = sr[5];
        c_fa = sr[12];
        const float me0 = sr[13];
        c_fv = fv0;
        ef_dx_r = fx0 - ego_x_r;
        em_dx_r = (mx0 - ego_x_r) * me0 + (1.0f - me0) * 100.0f;
        ef_dv_r = ego_v_r - fv0;
        em_dv_r = (ego_v_r - mv0) * me0;
        c_m0 = mr[0]; c_m1 = mr[1]; c_m2 = mr[2];
    }
    const float ptg    = idm_params[bm * 5 + 1];
    const float pjam   = idm_params[bm * 5 + 2];
    const float pamax  = idm_params[bm * 5 + 3];
    const float pinv_v0 = 1.0f / idm_params[bm * 5 + 0];
    const float pinv_gd = 1.0f / (2.0f * sqrtf(pamax * idm_params[bm * 5 + 4]));

    float* out_disp = out;
    float* out_act  = out + NB * 51;
    float* out_fat  = out + NB * (51 + 50);
    float* out_mat  = out + NB * (51 + 100);
    if (tid < 16) out_disp[bm * 51] = 0.0f;

    // producer slot for s_a writes
    const int kcw = w >> 1;
    const int Lw  = lm + 16 * ((w & 1) * 2 + (lq >> 1));
    const int e0w = (lq & 1) * 4;

    for (int t = 0; t < NT; ++t) {
        // ---- prefetch next-step exogenous scalars (own elem) ----
        float nf_fv = 0, nf_mv = 0, nf_fx = 0, nf_mx = 0, nf_fa = 0, nf_me = 0;
        float nf_m0 = 0, nf_m1 = 0, nf_m2 = 0;
        if (t + 1 < NT) {
            const float* sp = idm_s + (size_t)bm * 714 + (t + 1) * 14;
            nf_fv = sp[1]; nf_mv = sp[2]; nf_fx = sp[4]; nf_mx = sp[5];
            nf_fa = sp[12]; nf_me = sp[13];
            const float* mp = merger_cs + (size_t)bm * 150 + (t + 1) * 3;
            nf_m0 = mp[0]; nf_m1 = mp[1]; nf_m2 = mp[2];
        }

        // ---- phase A: layer1 via swapped MFMA (A=W1dT, B=env lane-local) ----
        float bv[8];
        #pragma unroll
        for (int e = 0; e < 8; ++e) bv[e] = 0.0f;
        if (lq == 0) {
            bv[0] = ego_a_r; bv[1] = c_fa;    bv[2] = ego_v_r; bv[3] = c_fv;
            bv[4] = ef_dv_r; bv[5] = ef_dx_r; bv[6] = em_dv_r; bv[7] = em_dx_r;
        } else if (lq == 1) {
            bv[0] = c_m0; bv[1] = c_m1; bv[2] = c_m2;
        }
        short8 E0, E1, E2;
        #pragma unroll
        for (int e = 0; e < 8; ++e) {
            const float v = bv[e];
            const unsigned short q0 = bf16rn(v);
            const float r1 = v - bf16tof(q0);
            const unsigned short q1 = bf16rn(r1);
            E0[e] = (short)q0; E1[e] = (short)q1;
            E2[e] = (short)bf16rn(r1 - bf16tof(q1));
        }
        const short8 W1T1 = *(const short8*)&s_w1t12[0][tid][0];
        const short8 W1T2 = *(const short8*)&s_w1t12[1][tid][0];
        f32x4 d1a = {0,0,0,0}, d1b = {0,0,0,0}, d1c = {0,0,0,0};
        d1a = __builtin_amdgcn_mfma_f32_16x16x32_bf16(W1T0, E0, d1a, 0, 0, 0);
        d1b = __builtin_amdgcn_mfma_f32_16x16x32_bf16(W1T0, E1, d1b, 0, 0, 0);
        d1b = __builtin_amdgcn_mfma_f32_16x16x32_bf16(W1T1, E0, d1b, 0, 0, 0);
        d1c = __builtin_amdgcn_mfma_f32_16x16x32_bf16(W1T1, E1, d1c, 0, 0, 0);
        d1c = __builtin_amdgcn_mfma_f32_16x16x32_bf16(W1T0, E2, d1c, 0, 0, 0);
        d1c = __builtin_amdgcn_mfma_f32_16x16x32_bf16(W1T2, E0, d1c, 0, 0, 0);

        // lane holds h1[elem=lm][col=colbase+r]; split 3-level, share via s_a
        unsigned short a0[4], a1[4], a2[4];
        #pragma unroll
        for (int r = 0; r < 4; ++r) {
            const float hv = leaky(d1a[r] + d1b[r] + d1c[r] + hp[r]);
            const unsigned short q0 = bf16rn(hv);
            const float r1 = hv - bf16tof(q0);
            const unsigned short q1 = bf16rn(r1);
            a0[r] = q0; a1[r] = q1; a2[r] = bf16rn(r1 - bf16tof(q1));
        }
        *(uint2*)&s_a[kcw][0][Lw][e0w] = make_uint2(pk2(a0[0], a0[1]), pk2(a0[2], a0[3]));
        *(uint2*)&s_a[kcw][1][Lw][e0w] = make_uint2(pk2(a1[0], a1[1]), pk2(a1[2], a1[3]));
        *(uint2*)&s_a[kcw][2][Lw][e0w] = make_uint2(pk2(a2[0], a2[1]), pk2(a2[2], a2[3]));

        __syncthreads();   // B1: h1 fragments visible

        // ---- phase B: layer2 via swapped MFMA (A=W2T, B=h1 frags) ----
        f32x4 aA = {0,0,0,0}, aB = {0,0,0,0}, aC = {0,0,0,0};
        #pragma unroll
        for (int kc = 0; kc < 4; ++kc) {
            const short8 x0 = *(const short8*)&s_a[kc][0][l][0];
            const short8 x1 = *(const short8*)&s_a[kc][1][l][0];
            const short8 x2 = *(const short8*)&s_a[kc][2][l][0];
            const short8 w2l2 = *(const short8*)&s_w2l2[kc][tid][0];
            aA = __builtin_amdgcn_mfma_f32_16x16x32_bf16(W2T0[kc], x0, aA, 0, 0, 0);
            aB = __builtin_amdgcn_mfma_f32_16x16x32_bf16(W2T0[kc], x1, aB, 0, 0, 0);
            aB = __builtin_amdgcn_mfma_f32_16x16x32_bf16(W2T1[kc], x0, aB, 0, 0, 0);
            aC = __builtin_amdgcn_mfma_f32_16x16x32_bf16(W2T1[kc], x1, aC, 0, 0, 0);
            aC = __builtin_amdgcn_mfma_f32_16x16x32_bf16(W2T0[kc], x2, aC, 0, 0, 0);
            aC = __builtin_amdgcn_mfma_f32_16x16x32_bf16(w2l2,    x0, aC, 0, 0, 0);
        }
        // lane holds h2[elem=lm][j=colbase+r] -> partial head scores
        float fsc = 0.0f, msc = 0.0f;
        #pragma unroll
        for (int r = 0; r < 4; ++r) {
            const float h2 = leaky(aA[r] + aB[r] + aC[r] + b2r[r]);
            fsc += h2 * wfr[r];
            msc += h2 * wmr[r];
        }
        // reduce over lq (lanes lm, lm+16, lm+32, lm+48): 2 swizzles per score
        fsc += __shfl_xor(fsc, 16); fsc += __shfl_xor(fsc, 32);
        msc += __shfl_xor(msc, 16); msc += __shfl_xor(msc, 32);
        if (l < 16) *(float2*)&s_part[lm][w * 2] = make_float2(fsc, msc);

        __syncthreads();   // B2: head partials visible

        // ---- phase C: dynamics, redundant on all lanes (own elem bm) ----
        {
            const f32x4 p0 = *(const f32x4*)&s_part[lm][0];
            const f32x4 p1 = *(const f32x4*)&s_part[lm][4];
            const f32x4 p2 = *(const f32x4*)&s_part[lm][8];
            const f32x4 p3 = *(const f32x4*)&s_part[lm][12];
            const float fsum = bfv + p0.x + p0.z + p1.x + p1.z + p2.x + p2.z + p3.x + p3.z;
            const float msum = bmv + p0.y + p0.w + p1.y + p1.w + p2.y + p2.w + p3.y + p3.w;

            const float f_sc = fminf(fmaxf(fsum, -20.0f), 20.0f);
            const float m_sc = fminf(fmaxf(msum, -20.0f), 20.0f);
            const float dsc = 5.0f * (f_sc - m_sc);
            float fatt;
            if (dsc >= 0.0f) { const float ex = __expf(-dsc); fatt = 1.0f / (1.0f + ex); }
            else             { const float ex = __expf(dsc);  fatt = ex / (1.0f + ex); }
            const float matt = 1.0f - fatt;

            const float efa = idm_act_f(ego_v_r, ef_dv_r, ef_dx_r,
                                        pinv_v0, ptg, pjam, pamax, pinv_gd);
            const float ema = idm_act_f(ego_v_r, em_dv_r, em_dx_r,
                                        pinv_v0, ptg, pjam, pamax, pinv_gd);
            const float a2n = fatt * efa + matt * ema;

            const float delta = ego_v_r * 0.1f + 0.005f * a2n;
            disp_r  += delta;
            ego_x_r += delta;
            ego_v_r += a2n * 0.1f;
            ego_a_r  = a2n;

            if (tid < 16) {
                out_disp[bm * 51 + t + 1] = disp_r;
                out_act [bm * 50 + t]     = a2n;
                out_fat [bm * 50 + t]     = fatt;
                out_mat [bm * 50 + t]     = matt;
            }

            if (t + 1 < NT) {
                ef_dx_r = nf_fx - ego_x_r;
                em_dx_r = (nf_mx - ego_x_r) * nf_me + (1.0f - nf_me) * 100.0f;
                ef_dv_r = ego_v_r - nf_fv;
                em_dv_r = (ego_v_r - nf_mv) * nf_me;
                c_fa = nf_fa; c_fv = nf_fv;
                c_m0 = nf_m0; c_m1 = nf_m1; c_m2 = nf_m2;
            }
        }
        // no 3rd barrier: s_a rewrite (t+1) is fenced by B2;
        // s_part rewrite (t+1) is fenced by B1(t+1).
    }
}

extern "C" void kernel_launch(void* const* d_in, const int* in_sizes, int n_in,
                              void* d_out, int out_size, void* d_ws, size_t ws_size,
                              hipStream_t stream) {
    (void)in_sizes; (void)n_in; (void)d_ws; (void)ws_size; (void)out_size;
    const float* idm_params  = (const float*)d_in[0];
    const float* proj_latent = (const float*)d_in[1];
    const float* enc_h       = (const float*)d_in[2];
    const float* idm_s       = (const float*)d_in[3];
    const float* merger_cs   = (const float*)d_in[4];
    const float* scaler_mean = (const float*)d_in[5];
    const float* scaler_var  = (const float*)d_in[6];
    const float* W1          = (const float*)d_in[7];
    const float* b1          = (const float*)d_in[8];
    const float* W2          = (const float*)d_in[9];
    const float* b2          = (const float*)d_in[10];
    const float* Wf          = (const float*)d_in[11];
    const float* bfp         = (const float*)d_in[12];
    const float* Wm          = (const float*)d_in[13];
    const float* bmp         = (const float*)d_in[14];

    idm_rollout_kernel<<<dim3(NB / 16), dim3(512), 0, stream>>>(
        idm_params, proj_latent, enc_h, idm_s, merger_cs,
        scaler_mean, scaler_var, W1, b1, W2, b2, Wf, bfp, Wm, bmp,
        (float*)d_out);
}

// Round 10
// 210.881 us; speedup vs baseline: 1.6076x; 1.3552x over previous
//
#include <hip/hip_runtime.h>

#define NB 8192
#define NT 50

typedef short short8 __attribute__((ext_vector_type(8)));
typedef float f32x4 __attribute__((ext_vector_type(4)));

__device__ __forceinline__ float leaky(float x) { return x > 0.0f ? x : 0.3f * x; }

__device__ __forceinline__ unsigned short bf16rn(float v) {
    unsigned int u = __float_as_uint(v);
    unsigned int r = u + 0x7FFFu + ((u >> 16) & 1u);
    return (unsigned short)(r >> 16);
}
__device__ __forceinline__ float bf16tof(unsigned short h) {
    return __uint_as_float(((unsigned int)h) << 16);
}
__device__ __forceinline__ float frcp(float x) { return __builtin_amdgcn_rcpf(x); }

extern "C" __global__ __launch_bounds__(512, 2)
void idm_rollout_kernel(const float* __restrict__ idm_params,
                        const float* __restrict__ proj_latent,
                        const float* __restrict__ enc_h,
                        const float* __restrict__ idm_s,
                        const float* __restrict__ merger_cs,
                        const float* __restrict__ scaler_mean,
                        const float* __restrict__ scaler_var,
                        const float* __restrict__ W1,
                        const float* __restrict__ b1,
                        const float* __restrict__ W2,
                        const float* __restrict__ b2,
                        const float* __restrict__ Wf,
                        const float* __restrict__ bfp,
                        const float* __restrict__ Wm,
                        const float* __restrict__ bmp,
                        float* __restrict__ out)
{
    // h1 3-level fragments: [kchunk][lvl][slot-lane][e]
    __shared__ __align__(16) short s_a[4][3][64][8];       // 12 KB
    // W2^T level-2 fragments (per-thread private slice)
    __shared__ __align__(16) short s_w2l2[4][512][8];      // 32 KB
    // dynamic W1 rows 256..266 (env rows pre-scaled by inv_std)
    __shared__ __align__(16) float s_w1d[11][128];         // 5.5 KB
    // head partials: [elem][2*jtile + {f,m}], padded row stride 20
    __shared__ __align__(16) float s_part[16][20];         // 1.25 KB

    const int tid = threadIdx.x;       // 0..511
    const int w   = tid >> 6;          // wave = jtile (layer2)
    const int l   = tid & 63;
    const int lm  = l & 15;            // this lane's batch element (within block)
    const int lq  = l >> 4;
    const int b0  = blockIdx.x * 16;
    const int bm  = b0 + lm;
    const int colbase = w * 16 + lq * 4;   // this lane's 4 h1/h2 columns

    // ---- stage dynamic W1 rows; env rows scaled by inv_std ----
    for (int idx = tid; idx < 11 * 128; idx += 512) {
        const int r = idx >> 7, c = idx & 127;
        float wv_ = W1[(256 + r) * 128 + c];
        if (r < 8) wv_ *= 1.0f / sqrtf(scaler_var[r]);
        s_w1d[r][c] = wv_;
    }

    // ---- W2^T A-frags: lvl0/1 in regs, lvl2 in LDS ----
    short8 W2T0[4], W2T1[4];
    #pragma unroll
    for (int kc = 0; kc < 4; ++kc) {
        short8 l2;
        #pragma unroll
        for (int e = 0; e < 8; ++e) {
            const int k = kc * 32 + lq * 8 + e;
            const float v = W2[k * 128 + w * 16 + lm];
            const unsigned short q0 = bf16rn(v);
            const float r1 = v - bf16tof(q0);
            const unsigned short q1 = bf16rn(r1);
            W2T0[kc][e] = (short)q0; W2T1[kc][e] = (short)q1;
            l2[e] = (short)bf16rn(r1 - bf16tof(q1));
        }
        *(short8*)&s_w2l2[kc][tid][0] = l2;
    }

    // ---- head constants for this lane's 4 cols ----
    const f32x4 b2r = *(const f32x4*)&b2[colbase];
    const f32x4 wfr = *(const f32x4*)&Wf[colbase];
    const f32x4 wmr = *(const f32x4*)&Wm[colbase];
    const float bfv = bfp[0];
    const float bmv = bmp[0];

    // ---- hpre for (elem lm, cols colbase..+3) ----
    f32x4 hp = *(const f32x4*)&b1[colbase];
    {
        const float* xl0 = proj_latent + (size_t)bm * 128;
        const float* xl1 = enc_h + (size_t)bm * 128;
        #pragma unroll 2
        for (int r0 = 0; r0 < 128; r0 += 4) {
            const f32x4 x = *(const f32x4*)&xl0[r0];
            #pragma unroll
            for (int j = 0; j < 4; ++j) {
                const f32x4 wq = *(const f32x4*)&W1[(r0 + j) * 128 + colbase];
                hp += x[j] * wq;
            }
        }
        #pragma unroll 2
        for (int r0 = 0; r0 < 128; r0 += 4) {
            const f32x4 x = *(const f32x4*)&xl1[r0];
            #pragma unroll
            for (int j = 0; j < 4; ++j) {
                const f32x4 wq = *(const f32x4*)&W1[(128 + r0 + j) * 128 + colbase];
                hp += x[j] * wq;
            }
        }
        #pragma unroll
        for (int rr = 0; rr < 8; ++rr) {   // fold -(mean*inv_std)@W1env
            const float c = scaler_mean[rr] * (1.0f / sqrtf(scaler_var[rr]));
            const f32x4 wq = *(const f32x4*)&W1[(256 + rr) * 128 + colbase];
            hp -= c * wq;
        }
    }

    // ---- per-lane dynamics state for elem bm (redundant across lanes) ----
    float ego_v_r, ego_a_r, ego_x_r, disp_r;
    float ef_dv_r, ef_dx_r, em_dv_r, em_dx_r;
    float c_fa, c_fv, c_m0, c_m1, c_m2;
    {
        const float* sr = idm_s + (size_t)bm * 714;     // 51*14
        const float* mr = merger_cs + (size_t)bm * 150;
        ego_v_r = sr[0]; ego_a_r = sr[11]; ego_x_r = sr[3]; disp_r = 0.0f;
        const float fv0 = sr[1], mv0 = sr[2], fx0 = sr[4], mx0 = sr[5];
        c_fa = sr[12];
        const float me0 = sr[13];
        c_fv = fv0;
        ef_dx_r = fx0 - ego_x_r;
        em_dx_r = (mx0 - ego_x_r) * me0 + (1.0f - me0) * 100.0f;
        ef_dv_r = ego_v_r - fv0;
        em_dv_r = (ego_v_r - mv0) * me0;
        c_m0 = mr[0]; c_m1 = mr[1]; c_m2 = mr[2];
    }
    const float ptg    = idm_params[bm * 5 + 1];
    const float pjam   = idm_params[bm * 5 + 2];
    const float pamax  = idm_params[bm * 5 + 3];
    const float pinv_v0 = 1.0f / idm_params[bm * 5 + 0];
    const float pinv_gd = 1.0f / (2.0f * sqrtf(pamax * idm_params[bm * 5 + 4]));

    float* out_disp = out;
    float* out_act  = out + NB * 51;
    float* out_fat  = out + NB * (51 + 50);
    float* out_mat  = out + NB * (51 + 100);
    if (tid < 16) out_disp[bm * 51] = 0.0f;

    // producer slot for s_a writes (col -> consumer-fragment mapping)
    const int kcw = w >> 1;
    const int Lw  = lm + 16 * ((w & 1) * 2 + (lq >> 1));
    const int e0w = (lq & 1) * 4;

    __syncthreads();   // s_w1d staged (s_w2l2 slots are same-thread)

    for (int t = 0; t < NT; ++t) {
        // ---- prefetch next-step exogenous scalars (own elem) ----
        float nf_fv = 0, nf_mv = 0, nf_fx = 0, nf_mx = 0, nf_fa = 0, nf_me = 0;
        float nf_m0 = 0, nf_m1 = 0, nf_m2 = 0;
        if (t + 1 < NT) {
            const float* sp = idm_s + (size_t)bm * 714 + (t + 1) * 14;
            nf_fv = sp[1]; nf_mv = sp[2]; nf_fx = sp[4]; nf_mx = sp[5];
            nf_fa = sp[12]; nf_me = sp[13];
            const float* mp = merger_cs + (size_t)bm * 150 + (t + 1) * 3;
            nf_m0 = mp[0]; nf_m1 = mp[1]; nf_m2 = mp[2];
        }

        // ---- phase A: layer-1 via VALU (11 dyn rows, env lane-local) ----
        float ev[11];
        ev[0] = ego_a_r; ev[1] = c_fa;    ev[2] = ego_v_r; ev[3] = c_fv;
        ev[4] = ef_dv_r; ev[5] = ef_dx_r; ev[6] = em_dv_r; ev[7] = em_dx_r;
        ev[8] = c_m0;    ev[9] = c_m1;    ev[10] = c_m2;
        f32x4 hq = hp;
        #pragma unroll
        for (int r = 0; r < 11; ++r) {
            const f32x4 wq = *(const f32x4*)&s_w1d[r][colbase];
            hq += ev[r] * wq;
        }
        const float h0 = leaky(hq.x), h1v = leaky(hq.y);
        const float h2v = leaky(hq.z), h3 = leaky(hq.w);

        // 3-level truncation split (residuals exact); pack pairs
        const unsigned int HM = 0xFFFF0000u;
        unsigned int ua = __float_as_uint(h0), ub = __float_as_uint(h1v);
        unsigned int uc = __float_as_uint(h2v), ud = __float_as_uint(h3);
        const unsigned int w00 = (ua >> 16) | (ub & HM);
        const unsigned int w01 = (uc >> 16) | (ud & HM);
        const float r1a = h0  - __uint_as_float(ua & HM);
        const float r1b = h1v - __uint_as_float(ub & HM);
        const float r1c = h2v - __uint_as_float(uc & HM);
        const float r1d = h3  - __uint_as_float(ud & HM);
        ua = __float_as_uint(r1a); ub = __float_as_uint(r1b);
        uc = __float_as_uint(r1c); ud = __float_as_uint(r1d);
        const unsigned int w10 = (ua >> 16) | (ub & HM);
        const unsigned int w11 = (uc >> 16) | (ud & HM);
        const float r2a = r1a - __uint_as_float(ua & HM);
        const float r2b = r1b - __uint_as_float(ub & HM);
        const float r2c = r1c - __uint_as_float(uc & HM);
        const float r2d = r1d - __uint_as_float(ud & HM);
        const unsigned int w20 = (__float_as_uint(r2a) >> 16) | (__float_as_uint(r2b) & HM);
        const unsigned int w21 = (__float_as_uint(r2c) >> 16) | (__float_as_uint(r2d) & HM);
        *(uint2*)&s_a[kcw][0][Lw][e0w] = make_uint2(w00, w01);
        *(uint2*)&s_a[kcw][1][Lw][e0w] = make_uint2(w10, w11);
        *(uint2*)&s_a[kcw][2][Lw][e0w] = make_uint2(w20, w21);

        __syncthreads();   // B1: h1 fragments visible

        // ---- phase B: layer-2 via swapped MFMA (A=W2T, B=h1 frags) ----
        f32x4 aA = {0,0,0,0}, aB = {0,0,0,0}, aC = {0,0,0,0};
        #pragma unroll
        for (int kc = 0; kc < 4; ++kc) {
            const short8 x0 = *(const short8*)&s_a[kc][0][l][0];
            const short8 x1 = *(const short8*)&s_a[kc][1][l][0];
            const short8 x2 = *(const short8*)&s_a[kc][2][l][0];
            const short8 w2l2 = *(const short8*)&s_w2l2[kc][tid][0];
            aA = __builtin_amdgcn_mfma_f32_16x16x32_bf16(W2T0[kc], x0, aA, 0, 0, 0);
            aB = __builtin_amdgcn_mfma_f32_16x16x32_bf16(W2T0[kc], x1, aB, 0, 0, 0);
            aB = __builtin_amdgcn_mfma_f32_16x16x32_bf16(W2T1[kc], x0, aB, 0, 0, 0);
            aC = __builtin_amdgcn_mfma_f32_16x16x32_bf16(W2T1[kc], x1, aC, 0, 0, 0);
            aC = __builtin_amdgcn_mfma_f32_16x16x32_bf16(W2T0[kc], x2, aC, 0, 0, 0);
            aC = __builtin_amdgcn_mfma_f32_16x16x32_bf16(w2l2,    x0, aC, 0, 0, 0);
        }
        // lane holds h2[elem=lm][j=colbase+r] -> partial head scores
        float fsc = 0.0f, msc = 0.0f;
        #pragma unroll
        for (int r = 0; r < 4; ++r) {
            const float h2 = leaky(aA[r] + aB[r] + aC[r] + b2r[r]);
            fsc += h2 * wfr[r];
            msc += h2 * wmr[r];
        }
        // reduce over lq (lanes lm, lm+16, lm+32, lm+48)
        fsc += __shfl_xor(fsc, 16); fsc += __shfl_xor(fsc, 32);
        msc += __shfl_xor(msc, 16); msc += __shfl_xor(msc, 32);
        if (l < 16) *(float2*)&s_part[lm][w * 2] = make_float2(fsc, msc);

        __syncthreads();   // B2: head partials visible

        // ---- phase C: dynamics, redundant on all lanes (own elem bm) ----
        {
            const f32x4 p0 = *(const f32x4*)&s_part[lm][0];
            const f32x4 p1 = *(const f32x4*)&s_part[lm][4];
            const f32x4 p2 = *(const f32x4*)&s_part[lm][8];
            const f32x4 p3 = *(const f32x4*)&s_part[lm][12];
            const float fsum = bfv + p0.x + p0.z + p1.x + p1.z + p2.x + p2.z + p3.x + p3.z;
            const float msum = bmv + p0.y + p0.w + p1.y + p1.w + p2.y + p2.w + p3.y + p3.w;

            const float f_sc = fminf(fmaxf(fsum, -20.0f), 20.0f);
            const float m_sc = fminf(fmaxf(msum, -20.0f), 20.0f);
            const float dsc = 5.0f * (f_sc - m_sc);
            const float ex  = __expf(-fabsf(dsc));
            const float inv = frcp(1.0f + ex);
            const float fatt = (dsc >= 0.0f) ? inv : ex * inv;
            const float matt = 1.0f - fatt;

            // shared IDM terms
            const float rr_ = ego_v_r * pinv_v0;
            const float rr2 = rr_ * rr_;
            const float base = pamax * (1.0f - rr2 * rr2);
            // follower branch
            const float dxf = fminf(fmaxf(ef_dx_r, 0.1f), 500.0f);
            const float gapf = ptg * ego_v_r + ego_v_r * ef_dv_r * pinv_gd;
            const float dgf = pjam + fmaxf(gapf, 0.0f);
            const float qf = dgf * frcp(dxf);
            const float efa = fminf(fmaxf(base - pamax * qf * qf, -6.0f), 6.0f);
            // merger branch
            const float dxm = fminf(fmaxf(em_dx_r, 0.1f), 500.0f);
            const float gapm = ptg * ego_v_r + ego_v_r * em_dv_r * pinv_gd;
            const float dgm = pjam + fmaxf(gapm, 0.0f);
            const float qm = dgm * frcp(dxm);
            const float ema = fminf(fmaxf(base - pamax * qm * qm, -6.0f), 6.0f);

            const float a2n = fatt * efa + matt * ema;

            const float delta = ego_v_r * 0.1f + 0.005f * a2n;
            disp_r  += delta;
            ego_x_r += delta;
            ego_v_r += a2n * 0.1f;
            ego_a_r  = a2n;

            if (tid < 16) {
                out_disp[bm * 51 + t + 1] = disp_r;
                out_act [bm * 50 + t]     = a2n;
                out_fat [bm * 50 + t]     = fatt;
                out_mat [bm * 50 + t]     = matt;
            }

            if (t + 1 < NT) {
                ef_dx_r = nf_fx - ego_x_r;
                em_dx_r = (nf_mx - ego_x_r) * nf_me + (1.0f - nf_me) * 100.0f;
                ef_dv_r = ego_v_r - nf_fv;
                em_dv_r = (ego_v_r - nf_mv) * nf_me;
                c_fa = nf_fa; c_fv = nf_fv;
                c_m0 = nf_m0; c_m1 = nf_m1; c_m2 = nf_m2;
            }
        }
        // no 3rd barrier: s_a rewrite (t+1) is fenced by B2;
        // s_part rewrite (t+1) is fenced by B1(t+1).
    }
}

extern "C" void kernel_launch(void* const* d_in, const int* in_sizes, int n_in,
                              void* d_out, int out_size, void* d_ws, size_t ws_size,
                              hipStream_t stream) {
    (void)in_sizes; (void)n_in; (void)d_ws; (void)ws_size; (void)out_size;
    const float* idm_params  = (const float*)d_in[0];
    const float* proj_latent = (const float*)d_in[1];
    const float* enc_h       = (const float*)d_in[2];
    const float* idm_s       = (const float*)d_in[3];
    const float* merger_cs   = (const float*)d_in[4];
    const float* scaler_mean = (const float*)d_in[5];
    const float* scaler_var  = (const float*)d_in[6];
    const float* W1          = (const float*)d_in[7];
    const float* b1          = (const float*)d_in[8];
    const float* W2          = (const float*)d_in[9];
    const float* b2          = (const float*)d_in[10];
    const float* Wf          = (const float*)d_in[11];
    const float* bfp         = (const float*)d_in[12];
    const float* Wm          = (const float*)d_in[13];
    const float* bmp         = (const float*)d_in[14];

    idm_rollout_kernel<<<dim3(NB / 16), dim3(512), 0, stream>>>(
        idm_params, proj_latent, enc_h, idm_s, merger_cs,
        scaler_mean, scaler_var, W1, b1, W2, b2, Wf, bfp, Wm, bmp,
        (float*)d_out);
}